// Round 5
// baseline (394.925 us; speedup 1.0000x reference)
//
#include <hip/hip_runtime.h>

// ---------------------------------------------------------------------------
// Attention_42674795053784 : cross-attention forward on MI355X (gfx950)
// R5: attn = 256-thr blocks, wave-pair m-split (LDS reads halved at full
//     occupancy), lsum via ones-row MFMA (linear partial combine; fixed-max
//     softmax), merged prep + merged QKV projection launches (4 launches).
// ---------------------------------------------------------------------------

typedef __bf16 bf16_t;
typedef __bf16 bf16x8 __attribute__((ext_vector_type(8)));
typedef float  f32x4  __attribute__((ext_vector_type(4)));

#define DIMM   1024
#define NHEAD  16
#define HDIM   64
#define NB     4
#define SEQ    2048
#define NROWS  (NB * SEQ)             // 8192
#define RMS_EPS 1.1920929e-07f
#define LOG2_10000_DIV32 0.4152410118609203f
// q scale: (1/8) * log2(e) so attn can use exp2 directly
#define QSCALE 0.18033688011112042f

// async global->LDS, 16B per lane; lds dest = base + lane*16 (wave-uniform base)
__device__ __forceinline__ void async16(const bf16_t* g, bf16_t* l) {
    __builtin_amdgcn_global_load_lds(
        (const __attribute__((address_space(1))) void*)g,
        (__attribute__((address_space(3))) void*)l, 16, 0, 0);
}

// --------------------------------------------------------------------------
// prep: fp32->bf16 casts (blocks 0..8191) + 3 weight transposes (8192..12287)
// --------------------------------------------------------------------------
__global__ __launch_bounds__(256)
void prep(const float* __restrict__ tgt, const float* __restrict__ src,
          bf16_t* __restrict__ tgtb, bf16_t* __restrict__ srcb,
          const float* __restrict__ Wq, const float* __restrict__ Wkv,
          const float* __restrict__ Wo, bf16_t* __restrict__ Wq_t,
          bf16_t* __restrict__ Wkv_t, bf16_t* __restrict__ Wo_t)
{
    __shared__ float t[32][33];
    int bid = blockIdx.x;
    if (bid < 8192) {                       // elementwise cast
        const float* x;
        bf16_t* y;
        if (bid < 4096) { x = tgt; y = tgtb; }
        else            { bid -= 4096; x = src; y = srcb; }
        const size_t i = ((size_t)bid * 256 + threadIdx.x) * 8;
        float4 f0 = ((const float4*)(x + i))[0];
        float4 f1 = ((const float4*)(x + i))[1];
        bf16_t v[8];
        v[0] = (bf16_t)f0.x; v[1] = (bf16_t)f0.y; v[2] = (bf16_t)f0.z; v[3] = (bf16_t)f0.w;
        v[4] = (bf16_t)f1.x; v[5] = (bf16_t)f1.y; v[6] = (bf16_t)f1.z; v[7] = (bf16_t)f1.w;
        *(int4*)(y + i) = *(int4*)v;
        return;
    }
    bid -= 8192;                            // weight transpose
    const float* W; bf16_t* Wt; int N, nx;
    if (bid < 1024)      { W = Wq;  Wt = Wq_t;  N = 1024; nx = 32; }
    else if (bid < 3072) { bid -= 1024; W = Wkv; Wt = Wkv_t; N = 2048; nx = 64; }
    else                 { bid -= 3072; W = Wo;  Wt = Wo_t;  N = 1024; nx = 32; }
    const int K  = 1024;
    const int n0 = (bid % nx) * 32;
    const int k0 = (bid / nx) * 32;
    const int tx = threadIdx.x & 31;
    const int ty = threadIdx.x >> 5;
#pragma unroll
    for (int i = ty; i < 32; i += 8)
        t[i][tx] = W[(size_t)(k0 + i) * N + n0 + tx];
    __syncthreads();
#pragma unroll
    for (int i = ty; i < 32; i += 8)
        Wt[(size_t)(n0 + i) * K + k0 + tx] = (bf16_t)t[tx][i];
}

// --------------------------------------------------------------------------
// Shared GEMM main loop (m97-style): acc = A[128 rows] * Bt[128 rows]^T
// --------------------------------------------------------------------------
#define GEMM_MAIN_LOOP(A_, Bt_, K_)                                           \
    __shared__ bf16_t As[128 * 64];                                           \
    __shared__ bf16_t Bs[128 * 64];                                           \
    const int tid  = threadIdx.x;                                             \
    const int lane = tid & 63;                                                \
    const int wave = tid >> 6;                                                \
    const int wm   = (wave >> 1) * 64;                                        \
    const int wn   = (wave & 1) * 64;                                         \
    const int lr   = lane & 15;                                               \
    const int quad = lane >> 4;                                               \
    {                                                                         \
        const int srow = lane >> 3;                                           \
        const int sslot = lane & 7;                                           \
        size_t aoff[4], boff[4];                                              \
        bf16_t *alp[4], *blp[4];                                              \
        _Pragma("unroll")                                                     \
        for (int t = 0; t < 4; ++t) {                                         \
            const int rb = wave * 32 + t * 8;                                 \
            const int r  = rb + srow;                                         \
            const int g  = sslot ^ (r & 7);                                   \
            aoff[t] = (size_t)(bm + r) * (K_) + g * 8;                        \
            boff[t] = (size_t)(bn + r) * (K_) + g * 8;                        \
            alp[t]  = As + rb * 64;                                           \
            blp[t]  = Bs + rb * 64;                                           \
        }                                                                     \
        for (int k0 = 0; k0 < (K_); k0 += 64) {                               \
            _Pragma("unroll")                                                 \
            for (int t = 0; t < 4; ++t) {                                     \
                async16((A_)  + aoff[t] + k0, alp[t]);                        \
                async16((Bt_) + boff[t] + k0, blp[t]);                        \
            }                                                                 \
            __syncthreads();                                                  \
            _Pragma("unroll")                                                 \
            for (int ks = 0; ks < 2; ++ks) {                                  \
                bf16x8 af[4], bfr[4];                                         \
                _Pragma("unroll")                                             \
                for (int i = 0; i < 4; ++i)                                   \
                    af[i] = *(const bf16x8*)&As[(wm + i * 16 + lr) * 64 +     \
                                (((ks * 4 + quad) ^ (lr & 7)) * 8)];          \
                _Pragma("unroll")                                             \
                for (int j = 0; j < 4; ++j)                                   \
                    bfr[j] = *(const bf16x8*)&Bs[(wn + j * 16 + lr) * 64 +    \
                                (((ks * 4 + quad) ^ (lr & 7)) * 8)];          \
                _Pragma("unroll")                                             \
                for (int i = 0; i < 4; ++i)                                   \
                    _Pragma("unroll")                                         \
                    for (int j = 0; j < 4; ++j)                               \
                        acc[i][j] = __builtin_amdgcn_mfma_f32_16x16x32_bf16(  \
                            af[i], bfr[j], acc[i][j], 0, 0, 0);               \
            }                                                                 \
            __syncthreads();                                                  \
        }                                                                     \
    }

// Fused per-head RMSNorm + RoPE epilogue (wave's 64 cols == one head).
__device__ __forceinline__ void norm_rope_store(
    f32x4 acc[4][4], const int* __restrict__ pos, const float* __restrict__ w,
    bf16_t* __restrict__ dstbase, int bm, int wm, int head,
    int lr, int quad, float oscale)
{
    float w0 = w[lr], w1 = w[16 + lr], w2 = w[32 + lr], w3 = w[48 + lr];
    const float invf0 = exp2f(-(float)lr * LOG2_10000_DIV32);
    const float invf1 = exp2f(-(float)(lr + 16) * LOG2_10000_DIV32);
#pragma unroll
    for (int i = 0; i < 4; ++i) {
        const int gr = bm + wm + i * 16 + quad * 4;
        int4 pos4 = *(const int4*)&pos[gr];
#pragma unroll
        for (int rg = 0; rg < 4; ++rg) {
            float x0 = acc[i][0][rg], x1 = acc[i][1][rg];
            float x2 = acc[i][2][rg], x3 = acc[i][3][rg];
            float ssum = x0 * x0 + x1 * x1 + x2 * x2 + x3 * x3;
#pragma unroll
            for (int off = 1; off < 16; off <<= 1)
                ssum += __shfl_xor(ssum, off, 64);
            const float rn = rsqrtf(ssum * (1.f / 64.f) + RMS_EPS);
            x0 *= rn * w0; x1 *= rn * w1; x2 *= rn * w2; x3 *= rn * w3;
            const float p  = (float)((&pos4.x)[rg]);
            const float a0 = p * invf0, a1 = p * invf1;
            const float s0 = __sinf(a0), c0 = __cosf(a0);
            const float s1 = __sinf(a1), c1 = __cosf(a1);
            const int row = gr + rg;
            const int bb = row >> 11, si = row & 2047;
            bf16_t* dst = dstbase +
                ((size_t)(bb * NHEAD + head) * SEQ + si) * HDIM;
            dst[lr]      = (bf16_t)((x0 * c0 - x2 * s0) * oscale);
            dst[16 + lr] = (bf16_t)((x1 * c1 - x3 * s1) * oscale);
            dst[32 + lr] = (bf16_t)((x2 * c0 + x0 * s0) * oscale);
            dst[48 + lr] = (bf16_t)((x3 * c1 + x1 * s1) * oscale);
        }
    }
}

// --------------------------------------------------------------------------
// Merged Q + KV projection.  Blocks 0..511: Q GEMM (fused norm+rope, QSCALE).
// Blocks 512..1535: KV GEMM (K: fused norm+rope; V: m-permuted direct to vT).
// --------------------------------------------------------------------------
__global__ __launch_bounds__(256)
void gemm_qkv(const bf16_t* __restrict__ tgtb, const bf16_t* __restrict__ srcb,
              const bf16_t* __restrict__ Wq_t, const bf16_t* __restrict__ Wkv_t,
              const int* __restrict__ tpos, const int* __restrict__ spos,
              const float* __restrict__ qw, const float* __restrict__ kw,
              bf16_t* __restrict__ qb, bf16_t* __restrict__ kbuf,
              bf16_t* __restrict__ vT)
{
    const int bid = blockIdx.x;
    if (bid < 512) {                         // ---- Q projection ----
        const int bm = (bid >> 3) * 128;
        const int bn = (bid & 7) * 128;
        f32x4 acc[4][4] = {};
        GEMM_MAIN_LOOP(tgtb, Wq_t, 1024)
        const int head = (bn + wn) >> 6;
        norm_rope_store(acc, tpos, qw, qb, bm, wm, head, lr, quad, QSCALE);
    } else {                                 // ---- KV projection ----
        const int t2 = bid - 512;
        const int bm = (t2 >> 4) * 128;
        const int bn = (t2 & 15) * 128;
        f32x4 acc[4][4] = {};
        GEMM_MAIN_LOOP(srcb, Wkv_t, 1024)
        if (bn < 1024) {                     // K proj
            const int head = (bn + wn) >> 6;
            norm_rope_store(acc, spos, kw, kbuf, bm, wm, head, lr, quad, 1.0f);
        } else {                             // V proj, m-permuted to vT
#pragma unroll
            for (int i = 0; i < 4; ++i) {
                const int M0 = bm + wm + i * 16;
                const int b  = M0 >> 11;
                const int mB = M0 & 2047;
                const int chunkbase = mB & ~127;
                const int ksm  = (mB >> 5) & 3;
                const int bit4 = (mB >> 4) & 1;
                const int pbase = (ksm * 4 + quad) * 8 + bit4 * 4;
#pragma unroll
                for (int j = 0; j < 4; ++j) {
                    const int c = bn + wn + j * 16 + lr - 1024;
                    const int h = c >> 6;
                    const int d = c & 63;
                    bf16_t pk[4];
#pragma unroll
                    for (int rg = 0; rg < 4; ++rg) pk[rg] = (bf16_t)acc[i][j][rg];
                    bf16_t* dst = vT + ((size_t)(b * NHEAD + h) * HDIM + d) * SEQ
                                  + chunkbase + pbase;
                    *(int2*)dst = *(int2*)pk;
                }
            }
        }
    }
}

// --------------------------------------------------------------------------
// Output projection GEMM (fp32 out).
// --------------------------------------------------------------------------
__global__ __launch_bounds__(256)
void gemm_o(const bf16_t* __restrict__ A, const bf16_t* __restrict__ Bt,
            float* __restrict__ Cp)
{
    const int bm = blockIdx.y * 128;
    const int bn = blockIdx.x * 128;
    f32x4 acc[4][4] = {};
    GEMM_MAIN_LOOP(A, Bt, 1024)
#pragma unroll
    for (int i = 0; i < 4; ++i)
#pragma unroll
        for (int j = 0; j < 4; ++j) {
            const int r0 = bm + wm + i * 16 + quad * 4;
            const int c  = bn + wn + j * 16 + lr;
#pragma unroll
            for (int rg = 0; rg < 4; ++rg)
                Cp[(size_t)(r0 + rg) * 1024 + c] = acc[i][j][rg];
        }
}

// --------------------------------------------------------------------------
// Flash attention, fixed-max softmax (exp2 domain), register-resident P.
//   256 threads / 4 waves; block = 128 q-rows; wave w: q-half = w&1,
//   m-half of each 128-chunk = w>>1 (4 q-tiles x 2 ksm per wave).
//   lsum via ones-row MFMA (accumulates in C across chunks; no adds/shuffles).
//   Fixed-max softmax => partials linear: end combine O/l across wave pairs
//   through LDS (reusing the K/V tile space).
// --------------------------------------------------------------------------
__global__ __launch_bounds__(256)
void attn(const bf16_t* __restrict__ q, const bf16_t* __restrict__ k,
          const bf16_t* __restrict__ vT, bf16_t* __restrict__ xo)
{
    __shared__ __align__(16) char smem[33280];   // 32 KB tiles + 512 B lsum
    bf16_t* Ks = (bf16_t*)smem;                  // [128 m][64 d] swizzled
    bf16_t* Vs = (bf16_t*)(smem + 16384);        // [64 d][128 m'] swizzled
    float*  cbO = (float*)smem;                  // combine: 2 x 16 KB
    float*  cbL = (float*)(smem + 32768);        // combine: 2 x 64 floats

    const int q0   = blockIdx.x * 128;
    const int h    = blockIdx.y;
    const int b    = blockIdx.z;
    const int bh   = b * NHEAD + h;
    const int tid  = threadIdx.x;
    const int lane = tid & 63;
    const int wv   = tid >> 6;            // 0..3
    const int qh   = wv & 1;              // q-half
    const int mh   = wv >> 1;             // m-half
    const int lr   = lane & 15;
    const int quad = lane >> 4;

    const bf16_t* kb = k  + (size_t)bh * SEQ * HDIM;
    const bf16_t* vb = vT + (size_t)bh * HDIM * SEQ;

    // Q fragments (B-operand), 4 q-tiles x 2 d-halves over this wave's q-half
    bf16x8 aq[4][2];
#pragma unroll
    for (int t = 0; t < 4; ++t) {
        const bf16_t* qp = q + ((size_t)bh * SEQ + q0 + qh * 64 + t * 16 + lr) * HDIM;
        aq[t][0] = *(const bf16x8*)(qp + quad * 8);
        aq[t][1] = *(const bf16x8*)(qp + 32 + quad * 8);
    }

    // cooperative staging: 4 K-DMAs + 4 V-DMAs per wave (R3 pattern, 0-conflict)
    size_t koff[4], voff[4];
    bf16_t *klp[4], *vlp[4];
#pragma unroll
    for (int t = 0; t < 4; ++t) {
        const int rbk = wv * 32 + t * 8;
        const int rk  = rbk + (lane >> 3);
        const int gk  = (lane & 7) ^ (rk & 7);
        koff[t] = (size_t)rk * HDIM + gk * 8;
        klp[t]  = Ks + rbk * 64;
        const int rbv = wv * 16 + t * 4;
        const int rv  = rbv + (lane >> 4);
        const int gv  = (lane & 15) ^ (rv & 15);
        voff[t] = (size_t)rv * SEQ + gv * 8;
        vlp[t]  = Vs + rbv * 128;
    }

    f32x4 zero4 = {0.f, 0.f, 0.f, 0.f};
    f32x4 o[4][4];                        // [q-tile][d-tile] partial (m-half)
    f32x4 ol[4];                          // lsum partial via ones-MFMA
#pragma unroll
    for (int t = 0; t < 4; ++t) {
        ol[t] = zero4;
#pragma unroll
        for (int dt = 0; dt < 4; ++dt) o[t][dt] = zero4;
    }
    bf16x8 ones;
#pragma unroll
    for (int i = 0; i < 8; ++i) ones[i] = (bf16_t)1.0f;

    for (int m0 = 0; m0 < SEQ; m0 += 128) {
#pragma unroll
        for (int t = 0; t < 4; ++t) {
            async16(kb + (size_t)m0 * HDIM + koff[t], klp[t]);
            async16(vb + voff[t] + m0, vlp[t]);
        }
        __syncthreads();

#pragma unroll
        for (int kk = 0; kk < 2; ++kk) {
            const int ksm = mh * 2 + kk;            // this wave's 32-m group
            bf16x8 bp[4];
#pragma unroll
            for (int half = 0; half < 2; ++half) {
                const int mt = ksm * 2 + half;
                f32x4 s[4] = {zero4, zero4, zero4, zero4};
#pragma unroll
                for (int ksd = 0; ksd < 2; ++ksd) {
                    bf16x8 ak = *(const bf16x8*)&Ks[(mt * 16 + lr) * 64 +
                                    (((ksd * 4 + quad) ^ (lr & 7)) * 8)];
#pragma unroll
                    for (int t = 0; t < 4; ++t)
                        s[t] = __builtin_amdgcn_mfma_f32_16x16x32_bf16(
                            ak, aq[t][ksd], s[t], 0, 0, 0);
                }
#pragma unroll
                for (int t = 0; t < 4; ++t)
#pragma unroll
                    for (int r = 0; r < 4; ++r)
                        bp[t][half * 4 + r] = (bf16_t)exp2f(s[t][r]);
            }
            // PV + lsum (ones-row MFMA)
#pragma unroll
            for (int dt = 0; dt < 4; ++dt) {
                bf16x8 av = *(const bf16x8*)&Vs[(dt * 16 + lr) * 128 +
                                (((ksm * 4 + quad) ^ lr) * 8)];
#pragma unroll
                for (int t = 0; t < 4; ++t)
                    o[t][dt] = __builtin_amdgcn_mfma_f32_16x16x32_bf16(
                        av, bp[t], o[t][dt], 0, 0, 0);
            }
#pragma unroll
            for (int t = 0; t < 4; ++t)
                ol[t] = __builtin_amdgcn_mfma_f32_16x16x32_bf16(
                    ones, bp[t], ol[t], 0, 0, 0);
        }
        __syncthreads();
    }

    // ---- combine m-halves across wave pairs (linear: fixed-max softmax) ----
    if (wv >= 2) {
        float* myO = cbO + (wv - 2) * 4096;
#pragma unroll
        for (int t = 0; t < 4; ++t)
#pragma unroll
            for (int dt = 0; dt < 4; ++dt)
                *(f32x4*)&myO[((t * 4 + dt) * 64 + lane) * 4] = o[t][dt];
        if (quad == 0)
#pragma unroll
            for (int t = 0; t < 4; ++t)
                cbL[(wv - 2) * 64 + t * 16 + lr] = ol[t][0];
    }
    __syncthreads();
    if (wv < 2) {
        const float* thO = cbO + wv * 4096;
#pragma unroll
        for (int t = 0; t < 4; ++t) {
            const float lt = ol[t][0] + cbL[wv * 64 + t * 16 + lr];
            const float inv = 1.f / lt;
#pragma unroll
            for (int dt = 0; dt < 4; ++dt) {
                f32x4 add = *(const f32x4*)&thO[((t * 4 + dt) * 64 + lane) * 4];
                bf16_t pk[4];
#pragma unroll
                for (int rg = 0; rg < 4; ++rg)
                    pk[rg] = (bf16_t)((o[t][dt][rg] + add[rg]) * inv);
                bf16_t* dst = xo +
                    ((size_t)b * SEQ + q0 + wv * 64 + t * 16 + lr) * DIMM
                    + h * HDIM + dt * 16 + quad * 4;
                *(int2*)dst = *(int2*)pk;
            }
        }
    }
}

// --------------------------------------------------------------------------
extern "C" void kernel_launch(void* const* d_in, const int* in_sizes, int n_in,
                              void* d_out, int out_size, void* d_ws, size_t ws_size,
                              hipStream_t stream)
{
    const float* tgt  = (const float*)d_in[0];
    const float* src  = (const float*)d_in[1];
    const int*   tpos = (const int*)d_in[2];
    const int*   spos = (const int*)d_in[3];
    const float* Wq   = (const float*)d_in[4];
    const float* Wkv  = (const float*)d_in[5];
    const float* Wo   = (const float*)d_in[6];
    const float* qw   = (const float*)d_in[7];
    const float* kw   = (const float*)d_in[8];
    float* out = (float*)d_out;

    // workspace layout — 88 MB with buffer reuse
    char* ws = (char*)d_ws;
    const size_t MB = 1024 * 1024;
    bf16_t* Wq_t  = (bf16_t*)(ws + 0 * MB);    //  2 MB
    bf16_t* Wkv_t = (bf16_t*)(ws + 2 * MB);    //  4 MB
    bf16_t* Wo_t  = (bf16_t*)(ws + 6 * MB);    //  2 MB
    bf16_t* tgtb  = (bf16_t*)(ws + 8 * MB);    // 16 MB
    bf16_t* srcb  = (bf16_t*)(ws + 24 * MB);   // 16 MB (dead after gemm_qkv)
    bf16_t* xb    = (bf16_t*)(ws + 24 * MB);   //   ... reused: attn out
    bf16_t* qb    = (bf16_t*)(ws + 40 * MB);   // 16 MB  [b,h,n,64]
    bf16_t* kbuf  = (bf16_t*)(ws + 56 * MB);   // 16 MB  [b,h,m,64]
    bf16_t* vT    = (bf16_t*)(ws + 72 * MB);   // 16 MB  [b,h,64,m'] permuted

    // casts + weight transposes (one launch)
    prep<<<12288, 256, 0, stream>>>(tgt, src, tgtb, srcb,
                                    Wq, Wkv, Wo, Wq_t, Wkv_t, Wo_t);

    // Q + KV projections with fused norm/rope + V-permute epilogues (one launch)
    gemm_qkv<<<1536, 256, 0, stream>>>(tgtb, srcb, Wq_t, Wkv_t,
                                       tpos, spos, qw, kw, qb, kbuf, vT);

    // flash attention (exp2-domain fixed-max softmax, wave-pair m-split)
    attn<<<dim3(16, NHEAD, NB), 256, 0, stream>>>(qb, kbuf, vT, xb);

    // output projection (fp32 out)
    gemm_o<<<dim3(8, 64), 256, 0, stream>>>(xb, Wo_t, out);
}

// Round 6
// 346.329 us; speedup vs baseline: 1.1403x; 1.1403x over previous
//
#include <hip/hip_runtime.h>

// ---------------------------------------------------------------------------
// Attention_42674795053784 : cross-attention forward on MI355X (gfx950)
// R6: attn back to R3 structure (4 waves x 32q, full m per wave) but with
//     32x32x16 MFMAs (half the MFMA instrs, better rate); vT permutation
//     updated to the 32x32 PV B-frag order (within-16 only).
// ---------------------------------------------------------------------------

typedef __bf16 bf16_t;
typedef __bf16 bf16x8 __attribute__((ext_vector_type(8)));
typedef float  f32x4  __attribute__((ext_vector_type(4)));
typedef float  f32x16 __attribute__((ext_vector_type(16)));

#define DIMM   1024
#define NHEAD  16
#define HDIM   64
#define NB     4
#define SEQ    2048
#define NROWS  (NB * SEQ)             // 8192
#define RMS_EPS 1.1920929e-07f
#define LOG2_10000_DIV32 0.4152410118609203f
// q scale: (1/8) * log2(e) so attn can use exp2 directly
#define QSCALE 0.18033688011112042f

// async global->LDS, 16B per lane; lds dest = base + lane*16 (wave-uniform base)
__device__ __forceinline__ void async16(const bf16_t* g, bf16_t* l) {
    __builtin_amdgcn_global_load_lds(
        (const __attribute__((address_space(1))) void*)g,
        (__attribute__((address_space(3))) void*)l, 16, 0, 0);
}

// --------------------------------------------------------------------------
// prep: fp32->bf16 casts (blocks 0..8191) + 3 weight transposes (8192..12287)
// --------------------------------------------------------------------------
__global__ __launch_bounds__(256)
void prep(const float* __restrict__ tgt, const float* __restrict__ src,
          bf16_t* __restrict__ tgtb, bf16_t* __restrict__ srcb,
          const float* __restrict__ Wq, const float* __restrict__ Wkv,
          const float* __restrict__ Wo, bf16_t* __restrict__ Wq_t,
          bf16_t* __restrict__ Wkv_t, bf16_t* __restrict__ Wo_t)
{
    __shared__ float t[32][33];
    int bid = blockIdx.x;
    if (bid < 8192) {                       // elementwise cast
        const float* x;
        bf16_t* y;
        if (bid < 4096) { x = tgt; y = tgtb; }
        else            { bid -= 4096; x = src; y = srcb; }
        const size_t i = ((size_t)bid * 256 + threadIdx.x) * 8;
        float4 f0 = ((const float4*)(x + i))[0];
        float4 f1 = ((const float4*)(x + i))[1];
        bf16_t v[8];
        v[0] = (bf16_t)f0.x; v[1] = (bf16_t)f0.y; v[2] = (bf16_t)f0.z; v[3] = (bf16_t)f0.w;
        v[4] = (bf16_t)f1.x; v[5] = (bf16_t)f1.y; v[6] = (bf16_t)f1.z; v[7] = (bf16_t)f1.w;
        *(int4*)(y + i) = *(int4*)v;
        return;
    }
    bid -= 8192;                            // weight transpose
    const float* W; bf16_t* Wt; int N, nx;
    if (bid < 1024)      { W = Wq;  Wt = Wq_t;  N = 1024; nx = 32; }
    else if (bid < 3072) { bid -= 1024; W = Wkv; Wt = Wkv_t; N = 2048; nx = 64; }
    else                 { bid -= 3072; W = Wo;  Wt = Wo_t;  N = 1024; nx = 32; }
    const int K  = 1024;
    const int n0 = (bid % nx) * 32;
    const int k0 = (bid / nx) * 32;
    const int tx = threadIdx.x & 31;
    const int ty = threadIdx.x >> 5;
#pragma unroll
    for (int i = ty; i < 32; i += 8)
        t[i][tx] = W[(size_t)(k0 + i) * N + n0 + tx];
    __syncthreads();
#pragma unroll
    for (int i = ty; i < 32; i += 8)
        Wt[(size_t)(n0 + i) * K + k0 + tx] = (bf16_t)t[tx][i];
}

// --------------------------------------------------------------------------
// Shared GEMM main loop (m97-style): acc = A[128 rows] * Bt[128 rows]^T
// --------------------------------------------------------------------------
#define GEMM_MAIN_LOOP(A_, Bt_, K_)                                           \
    __shared__ bf16_t As[128 * 64];                                           \
    __shared__ bf16_t Bs[128 * 64];                                           \
    const int tid  = threadIdx.x;                                             \
    const int lane = tid & 63;                                                \
    const int wave = tid >> 6;                                                \
    const int wm   = (wave >> 1) * 64;                                        \
    const int wn   = (wave & 1) * 64;                                         \
    const int lr   = lane & 15;                                               \
    const int quad = lane >> 4;                                               \
    {                                                                         \
        const int srow = lane >> 3;                                           \
        const int sslot = lane & 7;                                           \
        size_t aoff[4], boff[4];                                              \
        bf16_t *alp[4], *blp[4];                                              \
        _Pragma("unroll")                                                     \
        for (int t = 0; t < 4; ++t) {                                         \
            const int rb = wave * 32 + t * 8;                                 \
            const int r  = rb + srow;                                         \
            const int g  = sslot ^ (r & 7);                                   \
            aoff[t] = (size_t)(bm + r) * (K_) + g * 8;                        \
            boff[t] = (size_t)(bn + r) * (K_) + g * 8;                        \
            alp[t]  = As + rb * 64;                                           \
            blp[t]  = Bs + rb * 64;                                           \
        }                                                                     \
        for (int k0 = 0; k0 < (K_); k0 += 64) {                               \
            _Pragma("unroll")                                                 \
            for (int t = 0; t < 4; ++t) {                                     \
                async16((A_)  + aoff[t] + k0, alp[t]);                        \
                async16((Bt_) + boff[t] + k0, blp[t]);                        \
            }                                                                 \
            __syncthreads();                                                  \
            _Pragma("unroll")                                                 \
            for (int ks = 0; ks < 2; ++ks) {                                  \
                bf16x8 af[4], bfr[4];                                         \
                _Pragma("unroll")                                             \
                for (int i = 0; i < 4; ++i)                                   \
                    af[i] = *(const bf16x8*)&As[(wm + i * 16 + lr) * 64 +     \
                                (((ks * 4 + quad) ^ (lr & 7)) * 8)];          \
                _Pragma("unroll")                                             \
                for (int j = 0; j < 4; ++j)                                   \
                    bfr[j] = *(const bf16x8*)&Bs[(wn + j * 16 + lr) * 64 +    \
                                (((ks * 4 + quad) ^ (lr & 7)) * 8)];          \
                _Pragma("unroll")                                             \
                for (int i = 0; i < 4; ++i)                                   \
                    _Pragma("unroll")                                         \
                    for (int j = 0; j < 4; ++j)                               \
                        acc[i][j] = __builtin_amdgcn_mfma_f32_16x16x32_bf16(  \
                            af[i], bfr[j], acc[i][j], 0, 0, 0);               \
            }                                                                 \
            __syncthreads();                                                  \
        }                                                                     \
    }

// Fused per-head RMSNorm + RoPE epilogue (wave's 64 cols == one head).
__device__ __forceinline__ void norm_rope_store(
    f32x4 acc[4][4], const int* __restrict__ pos, const float* __restrict__ w,
    bf16_t* __restrict__ dstbase, int bm, int wm, int head,
    int lr, int quad, float oscale)
{
    float w0 = w[lr], w1 = w[16 + lr], w2 = w[32 + lr], w3 = w[48 + lr];
    const float invf0 = exp2f(-(float)lr * LOG2_10000_DIV32);
    const float invf1 = exp2f(-(float)(lr + 16) * LOG2_10000_DIV32);
#pragma unroll
    for (int i = 0; i < 4; ++i) {
        const int gr = bm + wm + i * 16 + quad * 4;
        int4 pos4 = *(const int4*)&pos[gr];
#pragma unroll
        for (int rg = 0; rg < 4; ++rg) {
            float x0 = acc[i][0][rg], x1 = acc[i][1][rg];
            float x2 = acc[i][2][rg], x3 = acc[i][3][rg];
            float ssum = x0 * x0 + x1 * x1 + x2 * x2 + x3 * x3;
#pragma unroll
            for (int off = 1; off < 16; off <<= 1)
                ssum += __shfl_xor(ssum, off, 64);
            const float rn = rsqrtf(ssum * (1.f / 64.f) + RMS_EPS);
            x0 *= rn * w0; x1 *= rn * w1; x2 *= rn * w2; x3 *= rn * w3;
            const float p  = (float)((&pos4.x)[rg]);
            const float a0 = p * invf0, a1 = p * invf1;
            const float s0 = __sinf(a0), c0 = __cosf(a0);
            const float s1 = __sinf(a1), c1 = __cosf(a1);
            const int row = gr + rg;
            const int bb = row >> 11, si = row & 2047;
            bf16_t* dst = dstbase +
                ((size_t)(bb * NHEAD + head) * SEQ + si) * HDIM;
            dst[lr]      = (bf16_t)((x0 * c0 - x2 * s0) * oscale);
            dst[16 + lr] = (bf16_t)((x1 * c1 - x3 * s1) * oscale);
            dst[32 + lr] = (bf16_t)((x2 * c0 + x0 * s0) * oscale);
            dst[48 + lr] = (bf16_t)((x3 * c1 + x1 * s1) * oscale);
        }
    }
}

// --------------------------------------------------------------------------
// Merged Q + KV projection.  Blocks 0..511: Q GEMM (fused norm+rope, QSCALE).
// Blocks 512..1535: KV GEMM (K: fused norm+rope; V: m-permuted direct to vT).
// V permutation (32x32 PV A-frag order, within each 16-m group):
//   m' = 4*q + r  lives at  p' = 8*(q&1) + 4*(q>>1) + r   (q=quad, r=reg)
// --------------------------------------------------------------------------
__global__ __launch_bounds__(256)
void gemm_qkv(const bf16_t* __restrict__ tgtb, const bf16_t* __restrict__ srcb,
              const bf16_t* __restrict__ Wq_t, const bf16_t* __restrict__ Wkv_t,
              const int* __restrict__ tpos, const int* __restrict__ spos,
              const float* __restrict__ qw, const float* __restrict__ kw,
              bf16_t* __restrict__ qb, bf16_t* __restrict__ kbuf,
              bf16_t* __restrict__ vT)
{
    const int bid = blockIdx.x;
    if (bid < 512) {                         // ---- Q projection ----
        const int bm = (bid >> 3) * 128;
        const int bn = (bid & 7) * 128;
        f32x4 acc[4][4] = {};
        GEMM_MAIN_LOOP(tgtb, Wq_t, 1024)
        const int head = (bn + wn) >> 6;
        norm_rope_store(acc, tpos, qw, qb, bm, wm, head, lr, quad, QSCALE);
    } else {                                 // ---- KV projection ----
        const int t2 = bid - 512;
        const int bm = (t2 >> 4) * 128;
        const int bn = (t2 & 15) * 128;
        f32x4 acc[4][4] = {};
        GEMM_MAIN_LOOP(srcb, Wkv_t, 1024)
        if (bn < 1024) {                     // K proj
            const int head = (bn + wn) >> 6;
            norm_rope_store(acc, spos, kw, kbuf, bm, wm, head, lr, quad, 1.0f);
        } else {                             // V proj, m-permuted to vT
            const int pb = 8 * (quad & 1) + 4 * (quad >> 1);
#pragma unroll
            for (int i = 0; i < 4; ++i) {
                const int M0 = bm + wm + i * 16;
                const int b  = M0 >> 11;
                const int mB = M0 & 2047;        // 16-aligned token base
#pragma unroll
                for (int j = 0; j < 4; ++j) {
                    const int c = bn + wn + j * 16 + lr - 1024;
                    const int h = c >> 6;
                    const int d = c & 63;
                    bf16_t pk[4];
#pragma unroll
                    for (int rg = 0; rg < 4; ++rg) pk[rg] = (bf16_t)acc[i][j][rg];
                    bf16_t* dst = vT + ((size_t)(b * NHEAD + h) * HDIM + d) * SEQ
                                  + mB + pb;
                    *(int2*)dst = *(int2*)pk;
                }
            }
        }
    }
}

// --------------------------------------------------------------------------
// Output projection GEMM (fp32 out).
// --------------------------------------------------------------------------
__global__ __launch_bounds__(256)
void gemm_o(const bf16_t* __restrict__ A, const bf16_t* __restrict__ Bt,
            float* __restrict__ Cp)
{
    const int bm = blockIdx.y * 128;
    const int bn = blockIdx.x * 128;
    f32x4 acc[4][4] = {};
    GEMM_MAIN_LOOP(A, Bt, 1024)
#pragma unroll
    for (int i = 0; i < 4; ++i)
#pragma unroll
        for (int j = 0; j < 4; ++j) {
            const int r0 = bm + wm + i * 16 + quad * 4;
            const int c  = bn + wn + j * 16 + lr;
#pragma unroll
            for (int rg = 0; rg < 4; ++rg)
                Cp[(size_t)(r0 + rg) * 1024 + c] = acc[i][j][rg];
        }
}

// --------------------------------------------------------------------------
// Flash attention, fixed-max softmax (exp2 domain), register-resident P,
// 32x32x16 MFMAs.  4 waves x 32 q-rows, m-chunk 128 staged K/V.
//   S^T (32m x 32q) = mfma(A=K-frag, B=Q-frag): C/D col=q=lane&31,
//   row m = (reg&3)+8*(reg>>2)+4*(lane>>5).  P regs [0..7] -> PV MFMA c=0
//   (m 0..15), [8..15] -> c=1 (m 16..31); vT's within-16 permutation makes
//   the A-side k-order match.  O^T = mfma(V^T-frag, P-frag), 2 d-tiles.
// --------------------------------------------------------------------------
__global__ __launch_bounds__(256)
void attn(const bf16_t* __restrict__ q, const bf16_t* __restrict__ k,
          const bf16_t* __restrict__ vT, bf16_t* __restrict__ xo)
{
    __shared__ bf16_t Ks[128 * 64];       // [m][d], XOR-swizzled (8 slots)
    __shared__ bf16_t Vs[64 * 128];       // [d][m'], XOR-swizzled (16 slots)

    const int q0   = blockIdx.x * 128;
    const int h    = blockIdx.y;
    const int b    = blockIdx.z;
    const int bh   = b * NHEAD + h;
    const int tid  = threadIdx.x;
    const int lane = tid & 63;
    const int wv   = tid >> 6;            // 0..3
    const int l31  = lane & 31;
    const int hi   = lane >> 5;

    const bf16_t* kb = k  + (size_t)bh * SEQ * HDIM;
    const bf16_t* vb = vT + (size_t)bh * HDIM * SEQ;

    // Q B-frags: row q = q0 + wv*32 + l31, k(d) = kc*16 + hi*8 + j
    bf16x8 aq[4];
    {
        const bf16_t* qp = q + ((size_t)bh * SEQ + q0 + wv * 32 + l31) * HDIM + hi * 8;
        aq[0] = *(const bf16x8*)(qp);
        aq[1] = *(const bf16x8*)(qp + 16);
        aq[2] = *(const bf16x8*)(qp + 32);
        aq[3] = *(const bf16x8*)(qp + 48);
    }

    // cooperative staging (R3 pattern, 0-conflict)
    size_t koff[4], voff[4];
    bf16_t *klp[4], *vlp[4];
#pragma unroll
    for (int t = 0; t < 4; ++t) {
        const int rbk = wv * 32 + t * 8;
        const int rk  = rbk + (lane >> 3);
        const int gk  = (lane & 7) ^ (rk & 7);
        koff[t] = (size_t)rk * HDIM + gk * 8;
        klp[t]  = Ks + rbk * 64;
        const int rbv = wv * 16 + t * 4;
        const int rv  = rbv + (lane >> 4);
        const int gv  = (lane & 15) ^ (rv & 15);
        voff[t] = (size_t)rv * SEQ + gv * 8;
        vlp[t]  = Vs + rbv * 128;
    }

    f32x16 o0 = {}, o1 = {};              // d-tiles 0,1
    float lsum = 0.f;

    for (int m0 = 0; m0 < SEQ; m0 += 128) {
#pragma unroll
        for (int t = 0; t < 4; ++t) {
            async16(kb + (size_t)m0 * HDIM + koff[t], klp[t]);
            async16(vb + voff[t] + m0, vlp[t]);
        }
        __syncthreads();

#pragma unroll
        for (int mt = 0; mt < 4; ++mt) {
            // ---- S^T 32x32 tile ----
            f32x16 s = {};
#pragma unroll
            for (int kc = 0; kc < 4; ++kc) {
                bf16x8 ak = *(const bf16x8*)&Ks[(mt * 32 + l31) * 64 +
                                (((kc * 2 + hi) ^ (l31 & 7)) * 8)];
                s = __builtin_amdgcn_mfma_f32_32x32x16_bf16(ak, aq[kc], s, 0, 0, 0);
            }
            // ---- exp -> P frags (regs 0..7 -> c=0, 8..15 -> c=1) ----
            bf16x8 bp0, bp1;
#pragma unroll
            for (int j = 0; j < 8; ++j) {
                const float p0 = exp2f(s[j]);
                const float p1 = exp2f(s[8 + j]);
                lsum += p0 + p1;
                bp0[j] = (bf16_t)p0;
                bp1[j] = (bf16_t)p1;
            }
            // ---- PV: O^T += V^T * P^T (2 d-tiles x 2 m-subgroups) ----
#pragma unroll
            for (int dt = 0; dt < 2; ++dt) {
                const int rowb = (dt * 32 + l31) * 128;
                bf16x8 av0 = *(const bf16x8*)&Vs[rowb +
                                ((((mt * 4 + 0) + hi) ^ (l31 & 15)) * 8)];
                bf16x8 av1 = *(const bf16x8*)&Vs[rowb +
                                ((((mt * 4 + 2) + hi) ^ (l31 & 15)) * 8)];
                if (dt == 0) {
                    o0 = __builtin_amdgcn_mfma_f32_32x32x16_bf16(av0, bp0, o0, 0, 0, 0);
                    o0 = __builtin_amdgcn_mfma_f32_32x32x16_bf16(av1, bp1, o0, 0, 0, 0);
                } else {
                    o1 = __builtin_amdgcn_mfma_f32_32x32x16_bf16(av0, bp0, o1, 0, 0, 0);
                    o1 = __builtin_amdgcn_mfma_f32_32x32x16_bf16(av1, bp1, o1, 0, 0, 0);
                }
            }
        }
        __syncthreads();
    }

    // lsum: lanes L and L+32 hold the same q column
    lsum += __shfl_xor(lsum, 32, 64);
    const float inv = 1.f / lsum;

    // O^T C/D: col q = l31, row d' = (rg&3) + 8*(rg>>2) + 4*hi
    const size_t orow = (size_t)b * SEQ + q0 + wv * 32 + l31;
#pragma unroll
    for (int dt = 0; dt < 2; ++dt) {
#pragma unroll
        for (int g = 0; g < 4; ++g) {
            bf16_t pk[4];
#pragma unroll
            for (int u = 0; u < 4; ++u) {
                const float v = (dt == 0) ? o0[g * 4 + u] : o1[g * 4 + u];
                pk[u] = (bf16_t)(v * inv);
            }
            bf16_t* dst = xo + orow * DIMM + h * HDIM + dt * 32 + g * 8 + hi * 4;
            *(int2*)dst = *(int2*)pk;
        }
    }
}

// --------------------------------------------------------------------------
extern "C" void kernel_launch(void* const* d_in, const int* in_sizes, int n_in,
                              void* d_out, int out_size, void* d_ws, size_t ws_size,
                              hipStream_t stream)
{
    const float* tgt  = (const float*)d_in[0];
    const float* src  = (const float*)d_in[1];
    const int*   tpos = (const int*)d_in[2];
    const int*   spos = (const int*)d_in[3];
    const float* Wq   = (const float*)d_in[4];
    const float* Wkv  = (const float*)d_in[5];
    const float* Wo   = (const float*)d_in[6];
    const float* qw   = (const float*)d_in[7];
    const float* kw   = (const float*)d_in[8];
    float* out = (float*)d_out;

    // workspace layout — 88 MB with buffer reuse
    char* ws = (char*)d_ws;
    const size_t MB = 1024 * 1024;
    bf16_t* Wq_t  = (bf16_t*)(ws + 0 * MB);    //  2 MB
    bf16_t* Wkv_t = (bf16_t*)(ws + 2 * MB);    //  4 MB
    bf16_t* Wo_t  = (bf16_t*)(ws + 6 * MB);    //  2 MB
    bf16_t* tgtb  = (bf16_t*)(ws + 8 * MB);    // 16 MB
    bf16_t* srcb  = (bf16_t*)(ws + 24 * MB);   // 16 MB (dead after gemm_qkv)
    bf16_t* xb    = (bf16_t*)(ws + 24 * MB);   //   ... reused: attn out
    bf16_t* qb    = (bf16_t*)(ws + 40 * MB);   // 16 MB  [b,h,n,64]
    bf16_t* kbuf  = (bf16_t*)(ws + 56 * MB);   // 16 MB  [b,h,m,64]
    bf16_t* vT    = (bf16_t*)(ws + 72 * MB);   // 16 MB  [b,h,64,m'] permuted

    // casts + weight transposes (one launch)
    prep<<<12288, 256, 0, stream>>>(tgt, src, tgtb, srcb,
                                    Wq, Wkv, Wo, Wq_t, Wkv_t, Wo_t);

    // Q + KV projections with fused norm/rope + V-permute epilogues (one launch)
    gemm_qkv<<<1536, 256, 0, stream>>>(tgtb, srcb, Wq_t, Wkv_t,
                                       tpos, spos, qw, kw, qb, kbuf, vT);

    // flash attention (exp2-domain fixed-max softmax, 32x32x16 MFMAs)
    attn<<<dim3(16, NHEAD, NB), 256, 0, stream>>>(qb, kbuf, vT, xb);

    // output projection (fp32 out)
    gemm_o<<<dim3(8, 64), 256, 0, stream>>>(xb, Wo_t, out);
}

// Round 7
// 339.602 us; speedup vs baseline: 1.1629x; 1.0198x over previous
//
#include <hip/hip_runtime.h>

// ---------------------------------------------------------------------------
// Attention_42674795053784 : cross-attention forward on MI355X (gfx950)
// R7: attn reverted to the R3 optimum (2 q-tiles/wave, 16x16x32, 0-conflict)
//     + XCD-aware (b,h)-colocating block swizzle; vT permutation back to R3.
// ---------------------------------------------------------------------------

typedef __bf16 bf16_t;
typedef __bf16 bf16x8 __attribute__((ext_vector_type(8)));
typedef float  f32x4  __attribute__((ext_vector_type(4)));

#define DIMM   1024
#define NHEAD  16
#define HDIM   64
#define NB     4
#define SEQ    2048
#define NROWS  (NB * SEQ)             // 8192
#define RMS_EPS 1.1920929e-07f
#define LOG2_10000_DIV32 0.4152410118609203f
// q scale: (1/8) * log2(e) so attn can use exp2 directly
#define QSCALE 0.18033688011112042f

// async global->LDS, 16B per lane; lds dest = base + lane*16 (wave-uniform base)
__device__ __forceinline__ void async16(const bf16_t* g, bf16_t* l) {
    __builtin_amdgcn_global_load_lds(
        (const __attribute__((address_space(1))) void*)g,
        (__attribute__((address_space(3))) void*)l, 16, 0, 0);
}

// --------------------------------------------------------------------------
// prep: fp32->bf16 casts (blocks 0..8191) + 3 weight transposes (8192..12287)
// --------------------------------------------------------------------------
__global__ __launch_bounds__(256)
void prep(const float* __restrict__ tgt, const float* __restrict__ src,
          bf16_t* __restrict__ tgtb, bf16_t* __restrict__ srcb,
          const float* __restrict__ Wq, const float* __restrict__ Wkv,
          const float* __restrict__ Wo, bf16_t* __restrict__ Wq_t,
          bf16_t* __restrict__ Wkv_t, bf16_t* __restrict__ Wo_t)
{
    __shared__ float t[32][33];
    int bid = blockIdx.x;
    if (bid < 8192) {                       // elementwise cast
        const float* x;
        bf16_t* y;
        if (bid < 4096) { x = tgt; y = tgtb; }
        else            { bid -= 4096; x = src; y = srcb; }
        const size_t i = ((size_t)bid * 256 + threadIdx.x) * 8;
        float4 f0 = ((const float4*)(x + i))[0];
        float4 f1 = ((const float4*)(x + i))[1];
        bf16_t v[8];
        v[0] = (bf16_t)f0.x; v[1] = (bf16_t)f0.y; v[2] = (bf16_t)f0.z; v[3] = (bf16_t)f0.w;
        v[4] = (bf16_t)f1.x; v[5] = (bf16_t)f1.y; v[6] = (bf16_t)f1.z; v[7] = (bf16_t)f1.w;
        *(int4*)(y + i) = *(int4*)v;
        return;
    }
    bid -= 8192;                            // weight transpose
    const float* W; bf16_t* Wt; int N, nx;
    if (bid < 1024)      { W = Wq;  Wt = Wq_t;  N = 1024; nx = 32; }
    else if (bid < 3072) { bid -= 1024; W = Wkv; Wt = Wkv_t; N = 2048; nx = 64; }
    else                 { bid -= 3072; W = Wo;  Wt = Wo_t;  N = 1024; nx = 32; }
    const int K  = 1024;
    const int n0 = (bid % nx) * 32;
    const int k0 = (bid / nx) * 32;
    const int tx = threadIdx.x & 31;
    const int ty = threadIdx.x >> 5;
#pragma unroll
    for (int i = ty; i < 32; i += 8)
        t[i][tx] = W[(size_t)(k0 + i) * N + n0 + tx];
    __syncthreads();
#pragma unroll
    for (int i = ty; i < 32; i += 8)
        Wt[(size_t)(n0 + i) * K + k0 + tx] = (bf16_t)t[tx][i];
}

// --------------------------------------------------------------------------
// Shared GEMM main loop (m97-style): acc = A[128 rows] * Bt[128 rows]^T
// --------------------------------------------------------------------------
#define GEMM_MAIN_LOOP(A_, Bt_, K_)                                           \
    __shared__ bf16_t As[128 * 64];                                           \
    __shared__ bf16_t Bs[128 * 64];                                           \
    const int tid  = threadIdx.x;                                             \
    const int lane = tid & 63;                                                \
    const int wave = tid >> 6;                                                \
    const int wm   = (wave >> 1) * 64;                                        \
    const int wn   = (wave & 1) * 64;                                         \
    const int lr   = lane & 15;                                               \
    const int quad = lane >> 4;                                               \
    {                                                                         \
        const int srow = lane >> 3;                                           \
        const int sslot = lane & 7;                                           \
        size_t aoff[4], boff[4];                                              \
        bf16_t *alp[4], *blp[4];                                              \
        _Pragma("unroll")                                                     \
        for (int t = 0; t < 4; ++t) {                                         \
            const int rb = wave * 32 + t * 8;                                 \
            const int r  = rb + srow;                                         \
            const int g  = sslot ^ (r & 7);                                   \
            aoff[t] = (size_t)(bm + r) * (K_) + g * 8;                        \
            boff[t] = (size_t)(bn + r) * (K_) + g * 8;                        \
            alp[t]  = As + rb * 64;                                           \
            blp[t]  = Bs + rb * 64;                                           \
        }                                                                     \
        for (int k0 = 0; k0 < (K_); k0 += 64) {                               \
            _Pragma("unroll")                                                 \
            for (int t = 0; t < 4; ++t) {                                     \
                async16((A_)  + aoff[t] + k0, alp[t]);                        \
                async16((Bt_) + boff[t] + k0, blp[t]);                        \
            }                                                                 \
            __syncthreads();                                                  \
            _Pragma("unroll")                                                 \
            for (int ks = 0; ks < 2; ++ks) {                                  \
                bf16x8 af[4], bfr[4];                                         \
                _Pragma("unroll")                                             \
                for (int i = 0; i < 4; ++i)                                   \
                    af[i] = *(const bf16x8*)&As[(wm + i * 16 + lr) * 64 +     \
                                (((ks * 4 + quad) ^ (lr & 7)) * 8)];          \
                _Pragma("unroll")                                             \
                for (int j = 0; j < 4; ++j)                                   \
                    bfr[j] = *(const bf16x8*)&Bs[(wn + j * 16 + lr) * 64 +    \
                                (((ks * 4 + quad) ^ (lr & 7)) * 8)];          \
                _Pragma("unroll")                                             \
                for (int i = 0; i < 4; ++i)                                   \
                    _Pragma("unroll")                                         \
                    for (int j = 0; j < 4; ++j)                               \
                        acc[i][j] = __builtin_amdgcn_mfma_f32_16x16x32_bf16(  \
                            af[i], bfr[j], acc[i][j], 0, 0, 0);               \
            }                                                                 \
            __syncthreads();                                                  \
        }                                                                     \
    }

// Fused per-head RMSNorm + RoPE epilogue (wave's 64 cols == one head).
__device__ __forceinline__ void norm_rope_store(
    f32x4 acc[4][4], const int* __restrict__ pos, const float* __restrict__ w,
    bf16_t* __restrict__ dstbase, int bm, int wm, int head,
    int lr, int quad, float oscale)
{
    float w0 = w[lr], w1 = w[16 + lr], w2 = w[32 + lr], w3 = w[48 + lr];
    const float invf0 = exp2f(-(float)lr * LOG2_10000_DIV32);
    const float invf1 = exp2f(-(float)(lr + 16) * LOG2_10000_DIV32);
#pragma unroll
    for (int i = 0; i < 4; ++i) {
        const int gr = bm + wm + i * 16 + quad * 4;
        int4 pos4 = *(const int4*)&pos[gr];
#pragma unroll
        for (int rg = 0; rg < 4; ++rg) {
            float x0 = acc[i][0][rg], x1 = acc[i][1][rg];
            float x2 = acc[i][2][rg], x3 = acc[i][3][rg];
            float ssum = x0 * x0 + x1 * x1 + x2 * x2 + x3 * x3;
#pragma unroll
            for (int off = 1; off < 16; off <<= 1)
                ssum += __shfl_xor(ssum, off, 64);
            const float rn = rsqrtf(ssum * (1.f / 64.f) + RMS_EPS);
            x0 *= rn * w0; x1 *= rn * w1; x2 *= rn * w2; x3 *= rn * w3;
            const float p  = (float)((&pos4.x)[rg]);
            const float a0 = p * invf0, a1 = p * invf1;
            const float s0 = __sinf(a0), c0 = __cosf(a0);
            const float s1 = __sinf(a1), c1 = __cosf(a1);
            const int row = gr + rg;
            const int bb = row >> 11, si = row & 2047;
            bf16_t* dst = dstbase +
                ((size_t)(bb * NHEAD + head) * SEQ + si) * HDIM;
            dst[lr]      = (bf16_t)((x0 * c0 - x2 * s0) * oscale);
            dst[16 + lr] = (bf16_t)((x1 * c1 - x3 * s1) * oscale);
            dst[32 + lr] = (bf16_t)((x2 * c0 + x0 * s0) * oscale);
            dst[48 + lr] = (bf16_t)((x3 * c1 + x1 * s1) * oscale);
        }
    }
}

// --------------------------------------------------------------------------
// Merged Q + KV projection.  Blocks 0..511: Q GEMM (fused norm+rope, QSCALE).
// Blocks 512..1535: KV GEMM (K: fused norm+rope; V: m-permuted direct to vT).
// V permutation (R3 16x16 PV B-frag order):
//   m = chunk*128 + ksm*32 + bit4*16 + quad*4 + r  lives at
//   p = chunk*128 + (ksm*4+quad)*8 + bit4*4 + r
// --------------------------------------------------------------------------
__global__ __launch_bounds__(256)
void gemm_qkv(const bf16_t* __restrict__ tgtb, const bf16_t* __restrict__ srcb,
              const bf16_t* __restrict__ Wq_t, const bf16_t* __restrict__ Wkv_t,
              const int* __restrict__ tpos, const int* __restrict__ spos,
              const float* __restrict__ qw, const float* __restrict__ kw,
              bf16_t* __restrict__ qb, bf16_t* __restrict__ kbuf,
              bf16_t* __restrict__ vT)
{
    const int bid = blockIdx.x;
    if (bid < 512) {                         // ---- Q projection ----
        const int bm = (bid >> 3) * 128;
        const int bn = (bid & 7) * 128;
        f32x4 acc[4][4] = {};
        GEMM_MAIN_LOOP(tgtb, Wq_t, 1024)
        const int head = (bn + wn) >> 6;
        norm_rope_store(acc, tpos, qw, qb, bm, wm, head, lr, quad, QSCALE);
    } else {                                 // ---- KV projection ----
        const int t2 = bid - 512;
        const int bm = (t2 >> 4) * 128;
        const int bn = (t2 & 15) * 128;
        f32x4 acc[4][4] = {};
        GEMM_MAIN_LOOP(srcb, Wkv_t, 1024)
        if (bn < 1024) {                     // K proj
            const int head = (bn + wn) >> 6;
            norm_rope_store(acc, spos, kw, kbuf, bm, wm, head, lr, quad, 1.0f);
        } else {                             // V proj, m-permuted to vT (R3 order)
#pragma unroll
            for (int i = 0; i < 4; ++i) {
                const int M0 = bm + wm + i * 16;
                const int b  = M0 >> 11;
                const int mB = M0 & 2047;
                const int chunkbase = mB & ~127;
                const int ksm  = (mB >> 5) & 3;
                const int bit4 = (mB >> 4) & 1;
                const int pbase = (ksm * 4 + quad) * 8 + bit4 * 4;
#pragma unroll
                for (int j = 0; j < 4; ++j) {
                    const int c = bn + wn + j * 16 + lr - 1024;
                    const int h = c >> 6;
                    const int d = c & 63;
                    bf16_t pk[4];
#pragma unroll
                    for (int rg = 0; rg < 4; ++rg) pk[rg] = (bf16_t)acc[i][j][rg];
                    bf16_t* dst = vT + ((size_t)(b * NHEAD + h) * HDIM + d) * SEQ
                                  + chunkbase + pbase;
                    *(int2*)dst = *(int2*)pk;
                }
            }
        }
    }
}

// --------------------------------------------------------------------------
// Output projection GEMM (fp32 out).
// --------------------------------------------------------------------------
__global__ __launch_bounds__(256)
void gemm_o(const bf16_t* __restrict__ A, const bf16_t* __restrict__ Bt,
            float* __restrict__ Cp)
{
    const int bm = blockIdx.y * 128;
    const int bn = blockIdx.x * 128;
    f32x4 acc[4][4] = {};
    GEMM_MAIN_LOOP(A, Bt, 1024)
#pragma unroll
    for (int i = 0; i < 4; ++i)
#pragma unroll
        for (int j = 0; j < 4; ++j) {
            const int r0 = bm + wm + i * 16 + quad * 4;
            const int c  = bn + wn + j * 16 + lr;
#pragma unroll
            for (int rg = 0; rg < 4; ++rg)
                Cp[(size_t)(r0 + rg) * 1024 + c] = acc[i][j][rg];
        }
}

// --------------------------------------------------------------------------
// Flash attention (R3 optimum), fixed-max softmax (exp2 domain),
// register-resident P, 16x16x32 MFMAs, m-chunk 128, 4 waves x 32 q-rows.
// XCD-aware 1-D grid: all 16 q-blocks of one (b,h) share bid%8 -> one XCD
// under round-robin dispatch (8 heads/XCD -> K/V working set = 4 MB = L2).
// --------------------------------------------------------------------------
__global__ __launch_bounds__(256)
void attn(const bf16_t* __restrict__ q, const bf16_t* __restrict__ k,
          const bf16_t* __restrict__ vT, bf16_t* __restrict__ xo)
{
    __shared__ bf16_t Ks[128 * 64];       // [m][d], XOR-swizzled (8 slots)
    __shared__ bf16_t Vs[64 * 128];       // [d][m'], XOR-swizzled (16 slots)

    // swizzled decode: bid = xcd + 128*(grp&7) + 8*qx, grp>>3 == xcd
    const int bid = blockIdx.x;
    const int w   = bid >> 3;
    const int grp = (bid & 7) * 8 + (w >> 4);   // 0..63 = b*16+h
    const int q0  = (w & 15) * 128;
    const int h   = grp & 15;
    const int b   = grp >> 4;
    const int bh  = b * NHEAD + h;

    const int tid  = threadIdx.x;
    const int lane = tid & 63;
    const int wv   = tid >> 6;
    const int lr   = lane & 15;
    const int quad = lane >> 4;

    const bf16_t* kb = k  + (size_t)bh * SEQ * HDIM;
    const bf16_t* vb = vT + (size_t)bh * HDIM * SEQ;

    // Q fragments (B-operand), 2 q-tiles x 2 d-halves
    bf16x8 aq[2][2];
#pragma unroll
    for (int t = 0; t < 2; ++t) {
        const bf16_t* qp = q + ((size_t)bh * SEQ + q0 + wv * 32 + t * 16 + lr) * HDIM;
        aq[t][0] = *(const bf16x8*)(qp + quad * 8);
        aq[t][1] = *(const bf16x8*)(qp + 32 + quad * 8);
    }

    // cooperative staging: Ks 4 DMAs/wave (8 rows), Vs 4 DMAs/wave (4 rows)
    size_t koff[4], voff[4];
    bf16_t *klp[4], *vlp[4];
#pragma unroll
    for (int t = 0; t < 4; ++t) {
        const int rbk = wv * 32 + t * 8;
        const int rk  = rbk + (lane >> 3);
        const int gk  = (lane & 7) ^ (rk & 7);
        koff[t] = (size_t)rk * HDIM + gk * 8;
        klp[t]  = Ks + rbk * 64;
        const int rbv = wv * 16 + t * 4;
        const int rv  = rbv + (lane >> 4);
        const int gv  = (lane & 15) ^ (rv & 15);
        voff[t] = (size_t)rv * SEQ + gv * 8;
        vlp[t]  = Vs + rbv * 128;
    }

    f32x4 zero4 = {0.f, 0.f, 0.f, 0.f};
    f32x4 o[2][4];                        // [q-tile][d-tile]
    float lsum[2] = {0.f, 0.f};
#pragma unroll
    for (int t = 0; t < 2; ++t)
#pragma unroll
        for (int dt = 0; dt < 4; ++dt) o[t][dt] = zero4;

    for (int m0 = 0; m0 < SEQ; m0 += 128) {
#pragma unroll
        for (int t = 0; t < 4; ++t) {
            async16(kb + (size_t)m0 * HDIM + koff[t], klp[t]);
            async16(vb + voff[t] + m0, vlp[t]);
        }
        __syncthreads();

#pragma unroll
        for (int ksm = 0; ksm < 4; ++ksm) {
            // --- two 16-m S^T subtiles -> exp'd P values in registers ---
            float pe[2][8];
#pragma unroll
            for (int half = 0; half < 2; ++half) {
                const int mt = ksm * 2 + half;
                f32x4 s0 = zero4, s1 = zero4;
#pragma unroll
                for (int ksd = 0; ksd < 2; ++ksd) {
                    bf16x8 ak = *(const bf16x8*)&Ks[(mt * 16 + lr) * 64 +
                                    (((ksd * 4 + quad) ^ (lr & 7)) * 8)];
                    s0 = __builtin_amdgcn_mfma_f32_16x16x32_bf16(ak, aq[0][ksd], s0, 0, 0, 0);
                    s1 = __builtin_amdgcn_mfma_f32_16x16x32_bf16(ak, aq[1][ksd], s1, 0, 0, 0);
                }
#pragma unroll
                for (int r = 0; r < 4; ++r) {
                    const float p0 = exp2f(s0[r]);
                    const float p1 = exp2f(s1[r]);
                    lsum[0] += p0; lsum[1] += p1;
                    pe[0][half * 4 + r] = p0;
                    pe[1][half * 4 + r] = p1;
                }
            }
            // --- pack P fragments (B-operand of PV, k-order = vT's m-perm) ---
            bf16x8 bp0, bp1;
#pragma unroll
            for (int idx = 0; idx < 8; ++idx) {
                bp0[idx] = (bf16_t)pe[0][idx];
                bp1[idx] = (bf16_t)pe[1][idx];
            }
            // --- PV: O^T += V^T * P^T ---
#pragma unroll
            for (int dt = 0; dt < 4; ++dt) {
                bf16x8 av = *(const bf16x8*)&Vs[(dt * 16 + lr) * 128 +
                                (((ksm * 4 + quad) ^ lr) * 8)];
                o[0][dt] = __builtin_amdgcn_mfma_f32_16x16x32_bf16(av, bp0, o[0][dt], 0, 0, 0);
                o[1][dt] = __builtin_amdgcn_mfma_f32_16x16x32_bf16(av, bp1, o[1][dt], 0, 0, 0);
            }
        }
        __syncthreads();
    }

    // row-sum: per-lane partial (q=lr) reduced across the 4 quads
#pragma unroll
    for (int t = 0; t < 2; ++t) {
        lsum[t] += __shfl_xor(lsum[t], 16, 64);
        lsum[t] += __shfl_xor(lsum[t], 32, 64);
        lsum[t] = 1.f / lsum[t];
    }

    // O^T C/D: row=d=quad*4+rg, col=q=lr -> 4 consecutive d: 8B stores
#pragma unroll
    for (int t = 0; t < 2; ++t)
#pragma unroll
        for (int dt = 0; dt < 4; ++dt) {
            bf16_t pk[4];
#pragma unroll
            for (int rg = 0; rg < 4; ++rg)
                pk[rg] = (bf16_t)(o[t][dt][rg] * lsum[t]);
            bf16_t* dst = xo + ((size_t)b * SEQ + q0 + wv * 32 + t * 16 + lr) * DIMM
                          + h * HDIM + dt * 16 + quad * 4;
            *(int2*)dst = *(int2*)pk;
        }
}

// --------------------------------------------------------------------------
extern "C" void kernel_launch(void* const* d_in, const int* in_sizes, int n_in,
                              void* d_out, int out_size, void* d_ws, size_t ws_size,
                              hipStream_t stream)
{
    const float* tgt  = (const float*)d_in[0];
    const float* src  = (const float*)d_in[1];
    const int*   tpos = (const int*)d_in[2];
    const int*   spos = (const int*)d_in[3];
    const float* Wq   = (const float*)d_in[4];
    const float* Wkv  = (const float*)d_in[5];
    const float* Wo   = (const float*)d_in[6];
    const float* qw   = (const float*)d_in[7];
    const float* kw   = (const float*)d_in[8];
    float* out = (float*)d_out;

    // workspace layout — 88 MB with buffer reuse
    char* ws = (char*)d_ws;
    const size_t MB = 1024 * 1024;
    bf16_t* Wq_t  = (bf16_t*)(ws + 0 * MB);    //  2 MB
    bf16_t* Wkv_t = (bf16_t*)(ws + 2 * MB);    //  4 MB
    bf16_t* Wo_t  = (bf16_t*)(ws + 6 * MB);    //  2 MB
    bf16_t* tgtb  = (bf16_t*)(ws + 8 * MB);    // 16 MB
    bf16_t* srcb  = (bf16_t*)(ws + 24 * MB);   // 16 MB (dead after gemm_qkv)
    bf16_t* xb    = (bf16_t*)(ws + 24 * MB);   //   ... reused: attn out
    bf16_t* qb    = (bf16_t*)(ws + 40 * MB);   // 16 MB  [b,h,n,64]
    bf16_t* kbuf  = (bf16_t*)(ws + 56 * MB);   // 16 MB  [b,h,m,64]
    bf16_t* vT    = (bf16_t*)(ws + 72 * MB);   // 16 MB  [b,h,64,m'] permuted

    // casts + weight transposes (one launch)
    prep<<<12288, 256, 0, stream>>>(tgt, src, tgtb, srcb,
                                    Wq, Wkv, Wo, Wq_t, Wkv_t, Wo_t);

    // Q + KV projections with fused norm/rope + V-permute epilogues (one launch)
    gemm_qkv<<<1536, 256, 0, stream>>>(tgtb, srcb, Wq_t, Wkv_t,
                                       tpos, spos, qw, kw, qb, kbuf, vT);

    // flash attention (R3 optimum + XCD-aware swizzle)
    attn<<<1024, 256, 0, stream>>>(qb, kbuf, vT, xb);

    // output projection (fp32 out)
    gemm_o<<<dim3(8, 64), 256, 0, stream>>>(xb, Wo_t, out);
}